// Round 8
// baseline (239.405 us; speedup 1.0000x reference)
//
#include <hip/hip_runtime.h>
#include <math.h>

#define HID 256
#define CIN 288      // HID + POS
#define NTOK 16384   // B*N
#define NSEQ 2048
#define NH 4
#define DHD 64
#define TWO_PI 6.2831853071795864769f

typedef __attribute__((ext_vector_type(8))) short bf16x8;
typedef __attribute__((ext_vector_type(8))) unsigned short u16x8;
typedef __attribute__((ext_vector_type(4))) float f32x4;
typedef __attribute__((ext_vector_type(4))) unsigned short u16x4;

__device__ __forceinline__ ushort f2bf(float x) {
    unsigned u = __float_as_uint(x);
    u = (u + 0x7FFFu + ((u >> 16) & 1u)) >> 16;
    return (ushort)u;
}

__device__ __forceinline__ float bf2f(ushort u) {
    return __uint_as_float((unsigned)u << 16);
}

__device__ __forceinline__ float fast_exp2(float x) {
    return __builtin_amdgcn_exp2f(x);   // v_exp_f32
}

// pack two fp32 -> one dword of truncated bf16 (lo=a, hi=b) via v_perm_b32
__device__ __forceinline__ unsigned pack_bf_trunc(float a, float b) {
    return __builtin_amdgcn_perm(__float_as_uint(b), __float_as_uint(a), 0x07060302u);
}

// async global->LDS, 16 B per lane: LDS dst = base + lane*16 (wave-uniform base)
__device__ __forceinline__ void gload_lds16(const ushort* g, ushort* l) {
    __builtin_amdgcn_global_load_lds(
        (const __attribute__((address_space(1))) unsigned*)g,
        (__attribute__((address_space(3))) unsigned*)l, 16, 0, 0);
}

// LDS chunk swizzle for 128B rows (8 x 16B chunks/row): uniform bank classes
__device__ __forceinline__ int sw(int row) {
    return (((row >> 3) << 1) ^ row) & 7;
}

// ---------------------------------------------------------------------------
// Kernel 1: fuse in_proj with Wq/Wk/Wv -> bf16 Weff [768][288]; y==3 casts
// out_proj_w to bf16 (merged former cast_wo launch).
// ---------------------------------------------------------------------------
__global__ void fuse_w_kernel(const float* __restrict__ inW,
                              const float* __restrict__ Wq,
                              const float* __restrict__ Wk,
                              const float* __restrict__ Wv,
                              const float* __restrict__ Wo,
                              ushort* __restrict__ Wb,
                              ushort* __restrict__ WoB) {
    __shared__ float wrow[256];
    const int o = blockIdx.x;
    const int mat = blockIdx.y;
    const int t = threadIdx.x;
    if (mat == 3) {                   // cast out_proj_w row o
        if (t < 256) WoB[o * 256 + t] = f2bf(Wo[o * 256 + t]);
        return;
    }
    if (t < 256) wrow[t] = inW[(mat * 256 + o) * 256 + t];
    __syncthreads();
    if (t >= CIN) return;
    const float* Wm = (mat == 0) ? Wq : ((mat == 1) ? Wk : Wv);
    float acc = 0.f;
#pragma unroll 4
    for (int h = 0; h < 256; ++h) acc += wrow[h] * Wm[h * CIN + t];
    Wb[(size_t)(mat * 256 + o) * CIN + t] = f2bf(acc);
}

// ---------------------------------------------------------------------------
// Kernel 2: pos2embed + 2-layer MLP (replicates reference ez/cos(px) bug).
// ---------------------------------------------------------------------------
__global__ __launch_bounds__(128) void pos_mlp_kernel(
        const float* __restrict__ icoords, const float* __restrict__ qcoords,
        const float* __restrict__ w1, const float* __restrict__ b1,
        const float* __restrict__ w2, const float* __restrict__ b2,
        ushort* __restrict__ ip, ushort* __restrict__ qp) {
    __shared__ float sw1t[96 * 32];   // [e][r] transposed
    __shared__ float sb1[32];
    __shared__ float sw2[32 * 32];    // [c][r]
    __shared__ float sb2[32];
    const int t = threadIdx.x;
    for (int i = t; i < 96 * 32; i += 128) {
        const int e = i >> 5, r = i & 31;
        sw1t[i] = w1[r * 96 + e];
    }
    for (int i = t; i < 32 * 32; i += 128) sw2[i] = w2[i];
    if (t < 32) { sb1[t] = b1[t]; sb2[t] = b2[t]; }
    __syncthreads();

    const int tok = blockIdx.x * 128 + t;
    const int which = tok >> 14;
    const int m = tok & (NTOK - 1);
    const float* cr = (which ? qcoords : icoords) + m * 4;
    const float x = cr[1] * TWO_PI;
    const float y = cr[2] * TWO_PI;
    const float z = cr[3] * TWO_PI;

    f32x4 h4[8];
#pragma unroll
    for (int r4 = 0; r4 < 8; ++r4) h4[r4] = *(const f32x4*)&sb1[r4 * 4];

    for (int jj = 0; jj < 16; ++jj) {
        const float inv = 1.0f / (1.0f + 0.0625f * (float)jj);
        const float xs = x * inv, ys = y * inv, zs = z * inv;
        const float cx = __cosf(xs);
        float vals[6];
        int idx[6];
        vals[0] = __sinf(ys);  idx[0] = 2 * jj;
        vals[1] = __cosf(ys);  idx[1] = 2 * jj + 1;
        vals[2] = __sinf(xs);  idx[2] = 32 + 2 * jj;
        vals[3] = cx;          idx[3] = 32 + 2 * jj + 1;
        vals[4] = __sinf(zs);  idx[4] = 64 + 2 * jj;
        vals[5] = cx;          idx[5] = 64 + 2 * jj + 1;   // reference bug: cos of x
#pragma unroll
        for (int u = 0; u < 6; ++u) {
            const float ev = vals[u];
            const f32x4* wr = (const f32x4*)&sw1t[idx[u] * 32];
#pragma unroll
            for (int r4 = 0; r4 < 8; ++r4) h4[r4] += ev * wr[r4];
        }
    }
#pragma unroll
    for (int r4 = 0; r4 < 8; ++r4)
#pragma unroll
        for (int j = 0; j < 4; ++j) h4[r4][j] = fmaxf(h4[r4][j], 0.f);

    ushort* dst = (which ? qp : ip) + (size_t)m * CIN + 256;
#pragma unroll
    for (int c = 0; c < 32; ++c) {
        const f32x4* w4 = (const f32x4*)&sw2[c * 32];
        f32x4 a4 = h4[0] * w4[0];
#pragma unroll
        for (int r4 = 1; r4 < 8; ++r4) a4 += h4[r4] * w4[r4];
        dst[c] = f2bf(sb2[c] + (a4[0] + a4[1]) + (a4[2] + a4[3]));
    }
}

// ---------------------------------------------------------------------------
// Kernel 3: cast X / Q_in into cols 0..255 of the bf16 concat buffers.
// ---------------------------------------------------------------------------
__global__ void cast_x_kernel(const float* __restrict__ X, const float* __restrict__ Qin,
                              ushort* __restrict__ ip, ushort* __restrict__ qp) {
    const int which = blockIdx.y;
    const size_t f = ((size_t)blockIdx.x * 256 + threadIdx.x) * 8;
    const int row = (int)(f >> 8);
    const int col = (int)(f & 255);
    const float* src = which ? Qin : X;
    ushort* dst = which ? qp : ip;
    const float4 a = *(const float4*)(src + f);
    const float4 b = *(const float4*)(src + f + 4);
    u16x4 o0 = {f2bf(a.x), f2bf(a.y), f2bf(a.z), f2bf(a.w)};
    u16x4 o1 = {f2bf(b.x), f2bf(b.y), f2bf(b.z), f2bf(b.w)};
    *(u16x4*)(dst + (size_t)row * CIN + col) = o0;
    *(u16x4*)(dst + (size_t)row * CIN + col + 4) = o1;
}

// ---------------------------------------------------------------------------
// Kernel 4: QKV projection, bf16 MFMA with LDS-staged A (global_load_lds,
// double-buffered, one barrier per k-step). grid = (128, 12); block = 4 waves.
// ---------------------------------------------------------------------------
__global__ __launch_bounds__(256) void qkv_mfma(
        const ushort* __restrict__ qp, const ushort* __restrict__ ip,
        const ushort* __restrict__ Wb, const float* __restrict__ bias,
        ushort* __restrict__ qout, ushort* __restrict__ kout, ushort* __restrict__ vout) {
    __shared__ ushort SA[2 * 4096];   // 2 x 8 KB
    const int wv = threadIdx.x >> 6, lane = threadIdx.x & 63;
    const int l16 = lane & 15, quad = lane >> 4;
    const int m0b = blockIdx.x * 128;
    const int y = blockIdx.y;
    const int mat = y >> 2;
    const int n0 = y * 64;
    const ushort* A = (mat == 0) ? qp : ip;

    size_t asrc[2];
    int adst[2];
#pragma unroll
    for (int i = 0; i < 2; ++i) {
        const int idx = wv * 128 + i * 64 + lane;
        const int row = idx >> 2, cc = idx & 3;
        asrc[i] = (size_t)(m0b + row) * CIN + cc * 8;
        adst[i] = (wv * 128 + i * 64) * 8;
    }
    int aoff[2];
#pragma unroll
    for (int s = 0; s < 2; ++s)
        aoff[s] = ((32 * wv + 16 * s + l16) * 4 + quad) * 8;

    f32x4 acc[2][4];
#pragma unroll
    for (int s = 0; s < 2; ++s)
#pragma unroll
        for (int c = 0; c < 4; ++c) acc[s][c] = (f32x4){0.f, 0.f, 0.f, 0.f};

#pragma unroll
    for (int i = 0; i < 2; ++i)
        gload_lds16(A + asrc[i], SA + adst[i]);

    for (int t = 0; t < 9; ++t) {
        __syncthreads();
        if (t + 1 < 9) {
            const int bo = ((t + 1) & 1) * 4096;
#pragma unroll
            for (int i = 0; i < 2; ++i)
                gload_lds16(A + asrc[i] + (t + 1) * 32, SA + bo + adst[i]);
        }
        const ushort* buf = SA + (t & 1) * 4096;
        const int kk = t * 32;
        bf16x8 af[2], bf[4];
#pragma unroll
        for (int s = 0; s < 2; ++s)
            af[s] = *(const bf16x8*)(buf + aoff[s]);
#pragma unroll
        for (int c = 0; c < 4; ++c)
            bf[c] = *(const bf16x8*)(Wb + (size_t)(n0 + 16 * c + l16) * CIN + kk + quad * 8);
        if (mat < 2) {
#pragma unroll
            for (int s = 0; s < 2; ++s)
#pragma unroll
                for (int c = 0; c < 4; ++c)
                    acc[s][c] = __builtin_amdgcn_mfma_f32_16x16x32_bf16(bf[c], af[s], acc[s][c], 0, 0, 0);
        } else {
#pragma unroll
            for (int s = 0; s < 2; ++s)
#pragma unroll
                for (int c = 0; c < 4; ++c)
                    acc[s][c] = __builtin_amdgcn_mfma_f32_16x16x32_bf16(af[s], bf[c], acc[s][c], 0, 0, 0);
        }
    }

    const int h = y & 3;
    const int m0 = m0b + wv * 32;
    if (mat < 2) {
        const float scale = (mat == 0) ? (0.125f * 1.44269504088896f) : 1.0f;
        ushort* out = (mat == 0) ? qout : kout;
#pragma unroll
        for (int s = 0; s < 2; ++s) {
            const int tokm = m0 + 16 * s + l16;
            const int b = tokm >> 11, nn = tokm & (NSEQ - 1);
#pragma unroll
            for (int c = 0; c < 4; ++c) {
                const f32x4 b4 = *(const f32x4*)&bias[n0 + 16 * c + quad * 4];
                u16x4 w;
#pragma unroll
                for (int r = 0; r < 4; ++r) w[r] = f2bf((acc[s][c][r] + b4[r]) * scale);
                *(u16x4*)(out + ((size_t)(b * NH + h) * NSEQ + nn) * DHD + 16 * c + quad * 4) = w;
            }
        }
    } else {
#pragma unroll
        for (int s = 0; s < 2; ++s) {
            const int tok0 = m0 + 16 * s + quad * 4;
            const int b = tok0 >> 11, nn0 = tok0 & (NSEQ - 1);
#pragma unroll
            for (int c = 0; c < 4; ++c) {
                const int d = 16 * c + l16;
                const float bv = bias[n0 + d];
                u16x4 w;
#pragma unroll
                for (int r = 0; r < 4; ++r) w[r] = f2bf(acc[s][c][r] + bv);
                *(u16x4*)(vout + ((size_t)(b * NH + h) * DHD + d) * NSEQ + nn0) = w;
            }
        }
    }
}

// ---------------------------------------------------------------------------
// Kernel 5: MFMA flash attention, fixed-max softmax, LDS-staged K/V,
// SPLIT-K ACROSS BLOCKS (z = 0/1 -> keys z*1024..+1024). Fixed-max makes
// partial (O,l) plain sums; partials written bf16/f32, combined by attn_norm.
// Grid (16,32,2) = 1024 blocks -> 4 blocks/CU (vs 2), 16 waves/CU.
// ---------------------------------------------------------------------------
__global__ __launch_bounds__(256) void attn_kernel(
        const ushort* __restrict__ q, const ushort* __restrict__ k,
        const ushort* __restrict__ v, ushort* __restrict__ pO,
        float* __restrict__ lbuf) {
    __shared__ ushort SL[2 * 8192];   // 2 x (K 8 KB + V 8 KB)
    const int bh = blockIdx.y;
    const int z = blockIdx.z;
    const int wv = threadIdx.x >> 6;
    const int lane = threadIdx.x & 63;
    const int l16 = lane & 15, quad = lane >> 4;
    const int q0 = blockIdx.x * 128 + wv * 32;

    const ushort* qb = q + (size_t)bh * NSEQ * DHD;
    const ushort* kb = k + (size_t)bh * NSEQ * DHD + (size_t)z * 1024 * DHD;
    const ushort* vb = v + (size_t)bh * DHD * NSEQ + z * 1024;

    bf16x8 qf[2][2];
#pragma unroll
    for (int s = 0; s < 2; ++s)
#pragma unroll
        for (int hh = 0; hh < 2; ++hh)
            qf[s][hh] = *(const bf16x8*)(qb + (size_t)(q0 + 16 * s + l16) * DHD + 32 * hh + quad * 8);

    int ksrc[2], vsrc[2], sdst[2];
#pragma unroll
    for (int i = 0; i < 2; ++i) {
        const int idx = wv * 128 + i * 64 + lane;
        const int row = idx >> 3;
        const int cg = (idx & 7) ^ sw(row);
        ksrc[i] = row * DHD + cg * 8;
        vsrc[i] = row * NSEQ + cg * 8;
        sdst[i] = (wv * 128 + i * 64) * 8;
    }

    const int krow = 8 * (l16 >> 2) + (l16 & 3);   // key-slot permutation
    int koff[2][2][2];
    int voff[2][4];
#pragma unroll
    for (int sub = 0; sub < 2; ++sub) {
#pragma unroll
        for (int m = 0; m < 2; ++m) {
            const int row = sub * 32 + krow + 4 * m;
#pragma unroll
            for (int hh = 0; hh < 2; ++hh)
                koff[sub][m][hh] = (row * 8 + ((hh * 4 + quad) ^ sw(row))) * 8;
        }
#pragma unroll
        for (int c = 0; c < 4; ++c) {
            const int row = 16 * c + l16;
            voff[sub][c] = 4096 + (row * 8 + ((sub * 4 + quad) ^ sw(row))) * 8;
        }
    }

    f32x4 Oc[2][4];
#pragma unroll
    for (int s = 0; s < 2; ++s)
#pragma unroll
        for (int c = 0; c < 4; ++c) Oc[s][c] = (f32x4){0.f, 0.f, 0.f, 0.f};
    float lrun[2] = {0.f, 0.f};

#pragma unroll
    for (int i = 0; i < 2; ++i) {
        gload_lds16(kb + ksrc[i], SL + sdst[i]);
        gload_lds16(vb + vsrc[i], SL + 4096 + sdst[i]);
    }

    for (int t = 0; t < 16; ++t) {
        __syncthreads();
        if (t + 1 < 16) {
            const int bo = ((t + 1) & 1) * 8192;
            const int kt = (t + 1) * 64;
#pragma unroll
            for (int i = 0; i < 2; ++i) {
                gload_lds16(kb + (size_t)kt * DHD + ksrc[i], SL + bo + sdst[i]);
                gload_lds16(vb + kt + vsrc[i], SL + bo + 4096 + sdst[i]);
            }
        }
        const ushort* buf = SL + (t & 1) * 8192;

#pragma unroll
        for (int sub = 0; sub < 2; ++sub) {
            bf16x8 kf[2][2], vf[4];
#pragma unroll
            for (int m = 0; m < 2; ++m)
#pragma unroll
                for (int hh = 0; hh < 2; ++hh)
                    kf[m][hh] = *(const bf16x8*)(buf + koff[sub][m][hh]);
#pragma unroll
            for (int c = 0; c < 4; ++c)
                vf[c] = *(const bf16x8*)(buf + voff[sub][c]);

#pragma unroll
            for (int s = 0; s < 2; ++s) {
                f32x4 s0 = (f32x4){0.f, 0.f, 0.f, 0.f};
                f32x4 s1 = (f32x4){0.f, 0.f, 0.f, 0.f};
                s0 = __builtin_amdgcn_mfma_f32_16x16x32_bf16(kf[0][0], qf[s][0], s0, 0, 0, 0);
                s0 = __builtin_amdgcn_mfma_f32_16x16x32_bf16(kf[0][1], qf[s][1], s0, 0, 0, 0);
                s1 = __builtin_amdgcn_mfma_f32_16x16x32_bf16(kf[1][0], qf[s][0], s1, 0, 0, 0);
                s1 = __builtin_amdgcn_mfma_f32_16x16x32_bf16(kf[1][1], qf[s][1], s1, 0, 0, 0);

                float p0[4], p1[4];
#pragma unroll
                for (int r = 0; r < 4; ++r) {
                    p0[r] = fast_exp2(s0[r]);
                    p1[r] = fast_exp2(s1[r]);
                }
                lrun[s] += (p0[0] + p0[1]) + (p0[2] + p0[3]) + (p1[0] + p1[1]) + (p1[2] + p1[3]);

                union { bf16x8 v8; unsigned d[4]; } P;
                P.d[0] = pack_bf_trunc(p0[0], p0[1]);
                P.d[1] = pack_bf_trunc(p0[2], p0[3]);
                P.d[2] = pack_bf_trunc(p1[0], p1[1]);
                P.d[3] = pack_bf_trunc(p1[2], p1[3]);
#pragma unroll
                for (int c = 0; c < 4; ++c)
                    Oc[s][c] = __builtin_amdgcn_mfma_f32_16x16x32_bf16(vf[c], P.v8, Oc[s][c], 0, 0, 0);
            }
        }
    }

    // partial outputs: pO[z][tok][256] bf16, lbuf[z][bh][n] fp32
    const int b = bh >> 2, h = bh & 3;
    ushort* pOz = pO + (size_t)z * NTOK * HID;
#pragma unroll
    for (int s = 0; s < 2; ++s) {
        float ls = lrun[s];
        ls += __shfl_xor(ls, 16);
        ls += __shfl_xor(ls, 32);
        if (quad == 0)
            lbuf[(size_t)(z * 32 + bh) * NSEQ + q0 + 16 * s + l16] = ls;
        ushort* dst = pOz + (size_t)(b * NSEQ + q0 + 16 * s + l16) * HID + h * DHD;
#pragma unroll
        for (int c = 0; c < 4; ++c) {
            u16x4 w;
#pragma unroll
            for (int r = 0; r < 4; ++r) w[r] = f2bf(Oc[s][c][r]);
            *(u16x4*)(dst + 16 * c + quad * 4) = w;
        }
    }
}

// ---------------------------------------------------------------------------
// Kernel 6: combine split-K partials: abuf = (pO0 + pO1) / (l0 + l1), bf16.
// ---------------------------------------------------------------------------
__global__ __launch_bounds__(256) void attn_norm(
        const ushort* __restrict__ pO, const float* __restrict__ lbuf,
        ushort* __restrict__ abuf) {
    const size_t e = ((size_t)blockIdx.x * 256 + threadIdx.x) * 8;
    const int tok = (int)(e >> 8);
    const int c = (int)(e & 255);
    const int b = tok >> 11, n = tok & (NSEQ - 1);
    const int bh = b * NH + (c >> 6);
    const float l = lbuf[(size_t)bh * NSEQ + n] + lbuf[(size_t)(32 + bh) * NSEQ + n];
    const float linv = 1.0f / l;
    const u16x8 o0 = *(const u16x8*)(pO + e);
    const u16x8 o1 = *(const u16x8*)(pO + (size_t)NTOK * HID + e);
    u16x8 w;
#pragma unroll
    for (int j = 0; j < 8; ++j)
        w[j] = f2bf((bf2f(o0[j]) + bf2f(o1[j])) * linv);
    *(u16x8*)(abuf + e) = w;
}

// ---------------------------------------------------------------------------
// Kernel 7: out_proj (bf16 MFMA) + bias + residual + LayerNorm.
// ---------------------------------------------------------------------------
__global__ __launch_bounds__(256) void oproj_ln_mfma(
        const ushort* __restrict__ abuf, const float* __restrict__ Qin,
        const ushort* __restrict__ WoB, const float* __restrict__ bo,
        const float* __restrict__ g, const float* __restrict__ be,
        float* __restrict__ out) {
    __shared__ float yt[32][260];
    const int wv = threadIdx.x >> 6, lane = threadIdx.x & 63;
    const int l16 = lane & 15, quad = lane >> 4;
    const int m0 = blockIdx.x * 32;
    const int n0 = wv * 64;

    f32x4 acc[2][4];
#pragma unroll
    for (int s = 0; s < 2; ++s)
#pragma unroll
        for (int c = 0; c < 4; ++c) acc[s][c] = (f32x4){0.f, 0.f, 0.f, 0.f};

    for (int kk = 0; kk < HID; kk += 32) {
        bf16x8 af[2], bf[4];
#pragma unroll
        for (int s = 0; s < 2; ++s)
            af[s] = *(const bf16x8*)(abuf + (size_t)(m0 + 16 * s + l16) * HID + kk + quad * 8);
#pragma unroll
        for (int c = 0; c < 4; ++c)
            bf[c] = *(const bf16x8*)(WoB + (size_t)(n0 + 16 * c + l16) * HID + kk + quad * 8);
#pragma unroll
        for (int s = 0; s < 2; ++s)
#pragma unroll
            for (int c = 0; c < 4; ++c)
                acc[s][c] = __builtin_amdgcn_mfma_f32_16x16x32_bf16(af[s], bf[c], acc[s][c], 0, 0, 0);
    }

#pragma unroll
    for (int s = 0; s < 2; ++s)
#pragma unroll
        for (int c = 0; c < 4; ++c) {
            const int col = n0 + 16 * c + l16;
            const float bv = bo[col];
#pragma unroll
            for (int r = 0; r < 4; ++r) {
                const int row = 16 * s + quad * 4 + r;
                yt[row][col] = acc[s][c][r] + bv + Qin[(size_t)(m0 + row) * HID + col];
            }
        }
    __syncthreads();

    float gv[4], bev[4];
#pragma unroll
    for (int u = 0; u < 4; ++u) { gv[u] = g[lane + 64 * u]; bev[u] = be[lane + 64 * u]; }

    for (int rr = 0; rr < 8; ++rr) {
        const int row = wv * 8 + rr;
        float sm = 0.f, ssq = 0.f;
        float yv[4];
#pragma unroll
        for (int u = 0; u < 4; ++u) {
            yv[u] = yt[row][lane + 64 * u];
            sm += yv[u]; ssq += yv[u] * yv[u];
        }
#pragma unroll
        for (int off = 32; off >= 1; off >>= 1) {
            sm += __shfl_xor(sm, off);
            ssq += __shfl_xor(ssq, off);
        }
        const float mu = sm * (1.f / 256.f);
        const float rs = rsqrtf(fmaxf(ssq * (1.f / 256.f) - mu * mu, 0.f) + 1e-5f);
        float* dst = out + (size_t)(m0 + row) * HID;
#pragma unroll
        for (int u = 0; u < 4; ++u)
            dst[lane + 64 * u] = (yv[u] - mu) * rs * gv[u] + bev[u];
    }
}

// ---------------------------------------------------------------------------
extern "C" void kernel_launch(void* const* d_in, const int* in_sizes, int n_in,
                              void* d_out, int out_size, void* d_ws, size_t ws_size,
                              hipStream_t stream) {
    const float* inputs       = (const float*)d_in[0];
    const float* Q_in         = (const float*)d_in[1];
    const float* input_coords = (const float*)d_in[2];
    const float* Q_in_coords  = (const float*)d_in[3];
    const float* Wq           = (const float*)d_in[4];
    const float* Wk           = (const float*)d_in[5];
    const float* Wv           = (const float*)d_in[6];
    const float* in_proj_w    = (const float*)d_in[7];
    const float* in_proj_b    = (const float*)d_in[8];
    const float* out_proj_w   = (const float*)d_in[9];
    const float* out_proj_b   = (const float*)d_in[10];
    const float* ln_g         = (const float*)d_in[11];
    const float* ln_b         = (const float*)d_in[12];
    const float* pe_w1        = (const float*)d_in[13];
    const float* pe_b1        = (const float*)d_in[14];
    const float* pe_w2        = (const float*)d_in[15];
    const float* pe_b2        = (const float*)d_in[16];

    char* ws = (char*)d_ws;
    ushort* Wb   = (ushort*)(ws);              // 768*288*2     = 442368
    ushort* WoB  = (ushort*)(ws + 442368);     // 256*256*2     = 131072
    ushort* qp   = (ushort*)(ws + 573440);     // 16384*288*2   = 9437184
    ushort* ip   = (ushort*)(ws + 10010624);   // 9437184
    ushort* qbuf = (ushort*)(ws + 19447808);   // 8388608
    ushort* kbuf = (ushort*)(ws + 27836416);   // 8388608
    ushort* vbuf = (ushort*)(ws + 36225024);   // 8388608 (transposed [bh][64][n])
    ushort* abuf = (ushort*)(ws + 44613632);   // 8388608
    ushort* pO   = (ushort*)(ws + 53002240);   // 2*16384*256*2 = 16777216
    float*  lbuf = (float*) (ws + 69779456);   // 2*32*2048*4   = 524288 -> end 70303744

    fuse_w_kernel<<<dim3(256, 4), 320, 0, stream>>>(in_proj_w, Wq, Wk, Wv,
                                                    out_proj_w, Wb, WoB);
    pos_mlp_kernel<<<256, 128, 0, stream>>>(input_coords, Q_in_coords,
                                            pe_w1, pe_b1, pe_w2, pe_b2, ip, qp);
    cast_x_kernel<<<dim3(2048, 2), 256, 0, stream>>>(inputs, Q_in, ip, qp);
    qkv_mfma<<<dim3(128, 12), 256, 0, stream>>>(qp, ip, Wb, in_proj_b,
                                                qbuf, kbuf, vbuf);
    attn_kernel<<<dim3(16, 32, 2), 256, 0, stream>>>(qbuf, kbuf, vbuf, pO, lbuf);
    attn_norm<<<2048, 256, 0, stream>>>(pO, lbuf, abuf);
    oproj_ln_mfma<<<512, 256, 0, stream>>>(abuf, Q_in, WoB, out_proj_b,
                                           ln_g, ln_b, (float*)d_out);
}

// Round 10
// 238.521 us; speedup vs baseline: 1.0037x; 1.0037x over previous
//
#include <hip/hip_runtime.h>
#include <math.h>

#define HID 256
#define CIN 288      // HID + POS
#define NTOK 16384   // B*N
#define NSEQ 2048
#define NH 4
#define DHD 64
#define TWO_PI 6.2831853071795864769f

typedef __attribute__((ext_vector_type(8))) short bf16x8;
typedef __attribute__((ext_vector_type(4))) float f32x4;
typedef __attribute__((ext_vector_type(4))) unsigned short u16x4;

__device__ __forceinline__ ushort f2bf(float x) {
    unsigned u = __float_as_uint(x);
    u = (u + 0x7FFFu + ((u >> 16) & 1u)) >> 16;
    return (ushort)u;
}

__device__ __forceinline__ float fast_exp2(float x) {
    return __builtin_amdgcn_exp2f(x);   // v_exp_f32
}

// pack two fp32 -> one dword of truncated bf16 (lo=a, hi=b) via v_perm_b32
__device__ __forceinline__ unsigned pack_bf_trunc(float a, float b) {
    return __builtin_amdgcn_perm(__float_as_uint(b), __float_as_uint(a), 0x07060302u);
}

// async global->LDS, 16 B per lane. LDS dst MUST be wave-uniform (HW writes
// base + lane*16) — round 9's per-lane dst tripped nondeterminism.
__device__ __forceinline__ void gload_lds16(const ushort* g, ushort* l) {
    __builtin_amdgcn_global_load_lds(
        (const __attribute__((address_space(1))) unsigned*)g,
        (__attribute__((address_space(3))) unsigned*)l, 16, 0, 0);
}

// LDS chunk swizzle for 128B rows (8 x 16B chunks/row): uniform bank classes
__device__ __forceinline__ int sw(int row) {
    return (((row >> 3) << 1) ^ row) & 7;
}

// ---------------------------------------------------------------------------
// Kernel 1: fuse in_proj with Wq/Wk/Wv -> bf16 Weff [768][288]; y==3 casts
// out_proj_w to bf16 (merge proven in round 8).
// ---------------------------------------------------------------------------
__global__ void fuse_w_kernel(const float* __restrict__ inW,
                              const float* __restrict__ Wq,
                              const float* __restrict__ Wk,
                              const float* __restrict__ Wv,
                              const float* __restrict__ Wo,
                              ushort* __restrict__ Wb,
                              ushort* __restrict__ WoB) {
    __shared__ float wrow[256];
    const int o = blockIdx.x;
    const int mat = blockIdx.y;
    const int t = threadIdx.x;
    if (mat == 3) {                   // cast out_proj_w row o
        if (t < 256) WoB[o * 256 + t] = f2bf(Wo[o * 256 + t]);
        return;
    }
    if (t < 256) wrow[t] = inW[(mat * 256 + o) * 256 + t];
    __syncthreads();
    if (t >= CIN) return;
    const float* Wm = (mat == 0) ? Wq : ((mat == 1) ? Wk : Wv);
    float acc = 0.f;
#pragma unroll 4
    for (int h = 0; h < 256; ++h) acc += wrow[h] * Wm[h * CIN + t];
    Wb[(size_t)(mat * 256 + o) * CIN + t] = f2bf(acc);
}

// ---------------------------------------------------------------------------
// Kernel 2: pos2embed + 2-layer MLP (replicates reference ez/cos(px) bug).
// ---------------------------------------------------------------------------
__global__ __launch_bounds__(128) void pos_mlp_kernel(
        const float* __restrict__ icoords, const float* __restrict__ qcoords,
        const float* __restrict__ w1, const float* __restrict__ b1,
        const float* __restrict__ w2, const float* __restrict__ b2,
        ushort* __restrict__ ip, ushort* __restrict__ qp) {
    __shared__ float sw1t[96 * 32];   // [e][r] transposed
    __shared__ float sb1[32];
    __shared__ float sw2[32 * 32];    // [c][r]
    __shared__ float sb2[32];
    const int t = threadIdx.x;
    for (int i = t; i < 96 * 32; i += 128) {
        const int e = i >> 5, r = i & 31;
        sw1t[i] = w1[r * 96 + e];
    }
    for (int i = t; i < 32 * 32; i += 128) sw2[i] = w2[i];
    if (t < 32) { sb1[t] = b1[t]; sb2[t] = b2[t]; }
    __syncthreads();

    const int tok = blockIdx.x * 128 + t;
    const int which = tok >> 14;
    const int m = tok & (NTOK - 1);
    const float* cr = (which ? qcoords : icoords) + m * 4;
    const float x = cr[1] * TWO_PI;
    const float y = cr[2] * TWO_PI;
    const float z = cr[3] * TWO_PI;

    f32x4 h4[8];
#pragma unroll
    for (int r4 = 0; r4 < 8; ++r4) h4[r4] = *(const f32x4*)&sb1[r4 * 4];

    for (int jj = 0; jj < 16; ++jj) {
        const float inv = 1.0f / (1.0f + 0.0625f * (float)jj);
        const float xs = x * inv, ys = y * inv, zs = z * inv;
        const float cx = __cosf(xs);
        float vals[6];
        int idx[6];
        vals[0] = __sinf(ys);  idx[0] = 2 * jj;
        vals[1] = __cosf(ys);  idx[1] = 2 * jj + 1;
        vals[2] = __sinf(xs);  idx[2] = 32 + 2 * jj;
        vals[3] = cx;          idx[3] = 32 + 2 * jj + 1;
        vals[4] = __sinf(zs);  idx[4] = 64 + 2 * jj;
        vals[5] = cx;          idx[5] = 64 + 2 * jj + 1;   // reference bug: cos of x
#pragma unroll
        for (int u = 0; u < 6; ++u) {
            const float ev = vals[u];
            const f32x4* wr = (const f32x4*)&sw1t[idx[u] * 32];
#pragma unroll
            for (int r4 = 0; r4 < 8; ++r4) h4[r4] += ev * wr[r4];
        }
    }
#pragma unroll
    for (int r4 = 0; r4 < 8; ++r4)
#pragma unroll
        for (int j = 0; j < 4; ++j) h4[r4][j] = fmaxf(h4[r4][j], 0.f);

    ushort* dst = (which ? qp : ip) + (size_t)m * CIN + 256;
#pragma unroll
    for (int c = 0; c < 32; ++c) {
        const f32x4* w4 = (const f32x4*)&sw2[c * 32];
        f32x4 a4 = h4[0] * w4[0];
#pragma unroll
        for (int r4 = 1; r4 < 8; ++r4) a4 += h4[r4] * w4[r4];
        dst[c] = f2bf(sb2[c] + (a4[0] + a4[1]) + (a4[2] + a4[3]));
    }
}

// ---------------------------------------------------------------------------
// Kernel 3: cast X / Q_in into cols 0..255 of the bf16 concat buffers.
// ---------------------------------------------------------------------------
__global__ void cast_x_kernel(const float* __restrict__ X, const float* __restrict__ Qin,
                              ushort* __restrict__ ip, ushort* __restrict__ qp) {
    const int which = blockIdx.y;
    const size_t f = ((size_t)blockIdx.x * 256 + threadIdx.x) * 8;
    const int row = (int)(f >> 8);
    const int col = (int)(f & 255);
    const float* src = which ? Qin : X;
    ushort* dst = which ? qp : ip;
    const float4 a = *(const float4*)(src + f);
    const float4 b = *(const float4*)(src + f + 4);
    u16x4 o0 = {f2bf(a.x), f2bf(a.y), f2bf(a.z), f2bf(a.w)};
    u16x4 o1 = {f2bf(b.x), f2bf(b.y), f2bf(b.z), f2bf(b.w)};
    *(u16x4*)(dst + (size_t)row * CIN + col) = o0;
    *(u16x4*)(dst + (size_t)row * CIN + col + 4) = o1;
}

// ---------------------------------------------------------------------------
// Kernel 4: QKV projection, bf16 MFMA. grid = (128, 6); block = 4 waves
// (round-8 proven structure; col tile widened 64->128 so A is read 6x not
// 12x). y: mat = y>>1, col half = (y&1)*128. A tile (128 tok x 32 k) staged
// via global_load_lds with WAVE-UNIFORM LDS dst, double-buffered.
// ---------------------------------------------------------------------------
__global__ __launch_bounds__(256) void qkv_mfma(
        const ushort* __restrict__ qp, const ushort* __restrict__ ip,
        const ushort* __restrict__ Wb, const float* __restrict__ bias,
        ushort* __restrict__ qout, ushort* __restrict__ kout, ushort* __restrict__ vout) {
    __shared__ ushort SA[2 * 4096];   // 2 x 8 KB
    const int wv = threadIdx.x >> 6, lane = threadIdx.x & 63;
    const int l16 = lane & 15, quad = lane >> 4;
    const int m0b = blockIdx.x * 128;
    const int y = blockIdx.y;
    const int mat = y >> 1;
    const int n0 = (y & 1) * 128;              // within-mat col base
    const ushort* A = (mat == 0) ? qp : ip;

    size_t asrc[2];
    int adst[2];
#pragma unroll
    for (int i = 0; i < 2; ++i) {
        const int idx = wv * 128 + i * 64 + lane;
        const int row = idx >> 2, cc = idx & 3;
        asrc[i] = (size_t)(m0b + row) * CIN + cc * 8;
        adst[i] = (wv * 128 + i * 64) * 8;     // wave-uniform
    }
    int aoff[2];
#pragma unroll
    for (int s = 0; s < 2; ++s)
        aoff[s] = ((32 * wv + 16 * s + l16) * 4 + quad) * 8;

    f32x4 acc[2][8];
#pragma unroll
    for (int s = 0; s < 2; ++s)
#pragma unroll
        for (int c = 0; c < 8; ++c) acc[s][c] = (f32x4){0.f, 0.f, 0.f, 0.f};

#pragma unroll
    for (int i = 0; i < 2; ++i)
        gload_lds16(A + asrc[i], SA + adst[i]);

    for (int t = 0; t < 9; ++t) {
        __syncthreads();
        if (t < 8) {
            const int bo = ((t + 1) & 1) * 4096;
#pragma unroll
            for (int i = 0; i < 2; ++i)
                gload_lds16(A + asrc[i] + (t + 1) * 32, SA + bo + adst[i]);
        }
        const ushort* buf = SA + (t & 1) * 4096;
        const int kk = t * 32;
        bf16x8 af[2], bf[8];
#pragma unroll
        for (int s = 0; s < 2; ++s)
            af[s] = *(const bf16x8*)(buf + aoff[s]);
#pragma unroll
        for (int c = 0; c < 8; ++c)
            bf[c] = *(const bf16x8*)(Wb + (size_t)(mat * 256 + n0 + 16 * c + l16) * CIN + kk + quad * 8);
        if (mat < 2) {
#pragma unroll
            for (int s = 0; s < 2; ++s)
#pragma unroll
                for (int c = 0; c < 8; ++c)
                    acc[s][c] = __builtin_amdgcn_mfma_f32_16x16x32_bf16(bf[c], af[s], acc[s][c], 0, 0, 0);
        } else {
#pragma unroll
            for (int s = 0; s < 2; ++s)
#pragma unroll
                for (int c = 0; c < 8; ++c)
                    acc[s][c] = __builtin_amdgcn_mfma_f32_16x16x32_bf16(af[s], bf[c], acc[s][c], 0, 0, 0);
        }
    }

    const int m0 = m0b + wv * 32;
    if (mat < 2) {
        // lane: token = m0 + 16s + l16; cols d = n0 + 16c + quad*4 + r
        const float scale = (mat == 0) ? (0.125f * 1.44269504088896f) : 1.0f;
        ushort* out = (mat == 0) ? qout : kout;
#pragma unroll
        for (int s = 0; s < 2; ++s) {
            const int tokm = m0 + 16 * s + l16;
            const int b = tokm >> 11, nn = tokm & (NSEQ - 1);
#pragma unroll
            for (int c = 0; c < 8; ++c) {
                const int d = n0 + 16 * c + quad * 4;
                const int h = d >> 6, dd = d & 63;
                const f32x4 b4 = *(const f32x4*)&bias[mat * 256 + d];
                u16x4 w;
#pragma unroll
                for (int r = 0; r < 4; ++r) w[r] = f2bf((acc[s][c][r] + b4[r]) * scale);
                *(u16x4*)(out + ((size_t)(b * NH + h) * NSEQ + nn) * DHD + dd) = w;
            }
        }
    } else {
        // lane: dim d = n0 + 16c + l16; tokens m0 + 16s + quad*4 .. +3
#pragma unroll
        for (int s = 0; s < 2; ++s) {
            const int tok0 = m0 + 16 * s + quad * 4;
            const int b = tok0 >> 11, nn0 = tok0 & (NSEQ - 1);
#pragma unroll
            for (int c = 0; c < 8; ++c) {
                const int d = n0 + 16 * c + l16;
                const int h = d >> 6, dd = d & 63;
                const float bv = bias[512 + d];
                u16x4 w;
#pragma unroll
                for (int r = 0; r < 4; ++r) w[r] = f2bf(acc[s][c][r] + bv);
                *(u16x4*)(vout + ((size_t)(b * NH + h) * DHD + dd) * NSEQ + nn0) = w;
            }
        }
    }
}

// ---------------------------------------------------------------------------
// Kernel 5: MFMA flash attention (round-7 proven form: fixed-max softmax,
// LDS-staged K/V double-buffered, one barrier/tile). Grid (16, 32).
// ---------------------------------------------------------------------------
__global__ __launch_bounds__(256) void attn_kernel(
        const ushort* __restrict__ q, const ushort* __restrict__ k,
        const ushort* __restrict__ v, ushort* __restrict__ out) {
    __shared__ ushort SL[2 * 8192];   // 2 x (K 8 KB + V 8 KB)
    const int bh = blockIdx.y;
    const int wv = threadIdx.x >> 6;
    const int lane = threadIdx.x & 63;
    const int l16 = lane & 15, quad = lane >> 4;
    const int q0 = blockIdx.x * 128 + wv * 32;

    const ushort* qb = q + (size_t)bh * NSEQ * DHD;
    const ushort* kb = k + (size_t)bh * NSEQ * DHD;
    const ushort* vb = v + (size_t)bh * DHD * NSEQ;

    bf16x8 qf[2][2];
#pragma unroll
    for (int s = 0; s < 2; ++s)
#pragma unroll
        for (int hh = 0; hh < 2; ++hh)
            qf[s][hh] = *(const bf16x8*)(qb + (size_t)(q0 + 16 * s + l16) * DHD + 32 * hh + quad * 8);

    int ksrc[2], vsrc[2], sdst[2];
#pragma unroll
    for (int i = 0; i < 2; ++i) {
        const int idx = wv * 128 + i * 64 + lane;
        const int row = idx >> 3;
        const int cg = (idx & 7) ^ sw(row);
        ksrc[i] = row * DHD + cg * 8;
        vsrc[i] = row * NSEQ + cg * 8;
        sdst[i] = (wv * 128 + i * 64) * 8;     // wave-uniform
    }

    const int krow = 8 * (l16 >> 2) + (l16 & 3);   // key-slot permutation
    int koff[2][2][2];
    int voff[2][4];
#pragma unroll
    for (int sub = 0; sub < 2; ++sub) {
#pragma unroll
        for (int m = 0; m < 2; ++m) {
            const int row = sub * 32 + krow + 4 * m;
#pragma unroll
            for (int hh = 0; hh < 2; ++hh)
                koff[sub][m][hh] = (row * 8 + ((hh * 4 + quad) ^ sw(row))) * 8;
        }
#pragma unroll
        for (int c = 0; c < 4; ++c) {
            const int row = 16 * c + l16;
            voff[sub][c] = 4096 + (row * 8 + ((sub * 4 + quad) ^ sw(row))) * 8;
        }
    }

    f32x4 Oc[2][4];
#pragma unroll
    for (int s = 0; s < 2; ++s)
#pragma unroll
        for (int c = 0; c < 4; ++c) Oc[s][c] = (f32x4){0.f, 0.f, 0.f, 0.f};
    float lrun[2] = {0.f, 0.f};

#pragma unroll
    for (int i = 0; i < 2; ++i) {
        gload_lds16(kb + ksrc[i], SL + sdst[i]);
        gload_lds16(vb + vsrc[i], SL + 4096 + sdst[i]);
    }

    for (int t = 0; t < 32; ++t) {
        __syncthreads();
        if (t + 1 < 32) {
            const int bo = ((t + 1) & 1) * 8192;
            const int kt = (t + 1) * 64;
#pragma unroll
            for (int i = 0; i < 2; ++i) {
                gload_lds16(kb + (size_t)kt * DHD + ksrc[i], SL + bo + sdst[i]);
                gload_lds16(vb + kt + vsrc[i], SL + bo + 4096 + sdst[i]);
            }
        }
        const ushort* buf = SL + (t & 1) * 8192;

#pragma unroll
        for (int sub = 0; sub < 2; ++sub) {
            bf16x8 kf[2][2], vf[4];
#pragma unroll
            for (int m = 0; m < 2; ++m)
#pragma unroll
                for (int hh = 0; hh < 2; ++hh)
                    kf[m][hh] = *(const bf16x8*)(buf + koff[sub][m][hh]);
#pragma unroll
            for (int c = 0; c < 4; ++c)
                vf[c] = *(const bf16x8*)(buf + voff[sub][c]);

#pragma unroll
            for (int s = 0; s < 2; ++s) {
                f32x4 s0 = (f32x4){0.f, 0.f, 0.f, 0.f};
                f32x4 s1 = (f32x4){0.f, 0.f, 0.f, 0.f};
                s0 = __builtin_amdgcn_mfma_f32_16x16x32_bf16(kf[0][0], qf[s][0], s0, 0, 0, 0);
                s0 = __builtin_amdgcn_mfma_f32_16x16x32_bf16(kf[0][1], qf[s][1], s0, 0, 0, 0);
                s1 = __builtin_amdgcn_mfma_f32_16x16x32_bf16(kf[1][0], qf[s][0], s1, 0, 0, 0);
                s1 = __builtin_amdgcn_mfma_f32_16x16x32_bf16(kf[1][1], qf[s][1], s1, 0, 0, 0);

                float p0[4], p1[4];
#pragma unroll
                for (int r = 0; r < 4; ++r) {
                    p0[r] = fast_exp2(s0[r]);
                    p1[r] = fast_exp2(s1[r]);
                }
                lrun[s] += (p0[0] + p0[1]) + (p0[2] + p0[3]) + (p1[0] + p1[1]) + (p1[2] + p1[3]);

                union { bf16x8 v8; unsigned d[4]; } P;
                P.d[0] = pack_bf_trunc(p0[0], p0[1]);
                P.d[1] = pack_bf_trunc(p0[2], p0[3]);
                P.d[2] = pack_bf_trunc(p1[0], p1[1]);
                P.d[3] = pack_bf_trunc(p1[2], p1[3]);
#pragma unroll
                for (int c = 0; c < 4; ++c)
                    Oc[s][c] = __builtin_amdgcn_mfma_f32_16x16x32_bf16(vf[c], P.v8, Oc[s][c], 0, 0, 0);
            }
        }
    }

    const int b = bh >> 2, h = bh & 3;
#pragma unroll
    for (int s = 0; s < 2; ++s) {
        float ls = lrun[s];
        ls += __shfl_xor(ls, 16);
        ls += __shfl_xor(ls, 32);
        const float linv = 1.0f / ls;
        ushort* dst = out + (size_t)(b * NSEQ + q0 + 16 * s + l16) * HID + h * DHD;
#pragma unroll
        for (int c = 0; c < 4; ++c) {
            u16x4 w;
#pragma unroll
            for (int r = 0; r < 4; ++r) w[r] = f2bf(Oc[s][c][r] * linv);
            *(u16x4*)(dst + 16 * c + quad * 4) = w;
        }
    }
}

// ---------------------------------------------------------------------------
// Kernel 6: out_proj (bf16 MFMA) + bias + residual + LayerNorm.
// ---------------------------------------------------------------------------
__global__ __launch_bounds__(256) void oproj_ln_mfma(
        const ushort* __restrict__ abuf, const float* __restrict__ Qin,
        const ushort* __restrict__ WoB, const float* __restrict__ bo,
        const float* __restrict__ g, const float* __restrict__ be,
        float* __restrict__ out) {
    __shared__ float yt[32][260];
    const int wv = threadIdx.x >> 6, lane = threadIdx.x & 63;
    const int l16 = lane & 15, quad = lane >> 4;
    const int m0 = blockIdx.x * 32;
    const int n0 = wv * 64;

    f32x4 acc[2][4];
#pragma unroll
    for (int s = 0; s < 2; ++s)
#pragma unroll
        for (int c = 0; c < 4; ++c) acc[s][c] = (f32x4){0.f, 0.f, 0.f, 0.f};

    for (int kk = 0; kk < HID; kk += 32) {
        bf16x8 af[2], bf[4];
#pragma unroll
        for (int s = 0; s < 2; ++s)
            af[s] = *(const bf16x8*)(abuf + (size_t)(m0 + 16 * s + l16) * HID + kk + quad * 8);
#pragma unroll
        for (int c = 0; c < 4; ++c)
            bf[c] = *(const bf16x8*)(WoB + (size_t)(n0 + 16 * c + l16) * HID + kk + quad * 8);
#pragma unroll
        for (int s = 0; s < 2; ++s)
#pragma unroll
            for (int c = 0; c < 4; ++c)
                acc[s][c] = __builtin_amdgcn_mfma_f32_16x16x32_bf16(af[s], bf[c], acc[s][c], 0, 0, 0);
    }

#pragma unroll
    for (int s = 0; s < 2; ++s)
#pragma unroll
        for (int c = 0; c < 4; ++c) {
            const int col = n0 + 16 * c + l16;
            const float bv = bo[col];
#pragma unroll
            for (int r = 0; r < 4; ++r) {
                const int row = 16 * s + quad * 4 + r;
                yt[row][col] = acc[s][c][r] + bv + Qin[(size_t)(m0 + row) * HID + col];
            }
        }
    __syncthreads();

    float gv[4], bev[4];
#pragma unroll
    for (int u = 0; u < 4; ++u) { gv[u] = g[lane + 64 * u]; bev[u] = be[lane + 64 * u]; }

    for (int rr = 0; rr < 8; ++rr) {
        const int row = wv * 8 + rr;
        float sm = 0.f, ssq = 0.f;
        float yv[4];
#pragma unroll
        for (int u = 0; u < 4; ++u) {
            yv[u] = yt[row][lane + 64 * u];
            sm += yv[u]; ssq += yv[u] * yv[u];
        }
#pragma unroll
        for (int off = 32; off >= 1; off >>= 1) {
            sm += __shfl_xor(sm, off);
            ssq += __shfl_xor(ssq, off);
        }
        const float mu = sm * (1.f / 256.f);
        const float rs = rsqrtf(fmaxf(ssq * (1.f / 256.f) - mu * mu, 0.f) + 1e-5f);
        float* dst = out + (size_t)(m0 + row) * HID;
#pragma unroll
        for (int u = 0; u < 4; ++u)
            dst[lane + 64 * u] = (yv[u] - mu) * rs * gv[u] + bev[u];
    }
}

// ---------------------------------------------------------------------------
extern "C" void kernel_launch(void* const* d_in, const int* in_sizes, int n_in,
                              void* d_out, int out_size, void* d_ws, size_t ws_size,
                              hipStream_t stream) {
    const float* inputs       = (const float*)d_in[0];
    const float* Q_in         = (const float*)d_in[1];
    const float* input_coords = (const float*)d_in[2];
    const float* Q_in_coords  = (const float*)d_in[3];
    const float* Wq           = (const float*)d_in[4];
    const float* Wk           = (const float*)d_in[5];
    const float* Wv           = (const float*)d_in[6];
    const float* in_proj_w    = (const float*)d_in[7];
    const float* in_proj_b    = (const float*)d_in[8];
    const float* out_proj_w   = (const float*)d_in[9];
    const float* out_proj_b   = (const float*)d_in[10];
    const float* ln_g         = (const float*)d_in[11];
    const float* ln_b         = (const float*)d_in[12];
    const float* pe_w1        = (const float*)d_in[13];
    const float* pe_b1        = (const float*)d_in[14];
    const float* pe_w2        = (const float*)d_in[15];
    const float* pe_b2        = (const float*)d_in[16];

    char* ws = (char*)d_ws;
    ushort* Wb   = (ushort*)(ws);              // 768*288*2     = 442368
    ushort* WoB  = (ushort*)(ws + 442368);     // 256*256*2     = 131072
    ushort* qp   = (ushort*)(ws + 573440);     // 16384*288*2   = 9437184
    ushort* ip   = (ushort*)(ws + 10010624);   // 9437184
    ushort* qbuf = (ushort*)(ws + 19447808);   // 8388608
    ushort* kbuf = (ushort*)(ws + 27836416);   // 8388608
    ushort* vbuf = (ushort*)(ws + 36225024);   // 8388608 (transposed [bh][64][n])
    ushort* abuf = (ushort*)(ws + 44613632);   // 8388608 -> end 53002240 bytes

    fuse_w_kernel<<<dim3(256, 4), 320, 0, stream>>>(in_proj_w, Wq, Wk, Wv,
                                                    out_proj_w, Wb, WoB);
    pos_mlp_kernel<<<256, 128, 0, stream>>>(input_coords, Q_in_coords,
                                            pe_w1, pe_b1, pe_w2, pe_b2, ip, qp);
    cast_x_kernel<<<dim3(2048, 2), 256, 0, stream>>>(inputs, Q_in, ip, qp);
    qkv_mfma<<<dim3(128, 6), 256, 0, stream>>>(qp, ip, Wb, in_proj_b,
                                               qbuf, kbuf, vbuf);
    attn_kernel<<<dim3(16, 32), 256, 0, stream>>>(qbuf, kbuf, vbuf, abuf);
    oproj_ln_mfma<<<512, 256, 0, stream>>>(abuf, Q_in, WoB, out_proj_b,
                                           ln_g, ln_b, (float*)d_out);
}